// Round 4
// baseline (536.304 us; speedup 1.0000x reference)
//
#include <hip/hip_runtime.h>

#define B 4
#define L 96
#define V 207
#define H 8
#define E 64
#define C 512            // H*E
#define LS (V*C)         // stride between consecutive l rows = 105984
#define TOPK 4
#define CCH 32           // corr: channels staged per K-step
#define NCH 4            // corr: channel-chunks (blocks) per (b,v)
#define TPAD 68          // agg LDS row pitch (floats): 68%32=4 -> row rotation

// workspace layout (byte offsets)
#define MV_OFF 0                          // float mean_value[B*V*L] (atomic-accumulated)
#define IDX_OFF (B*V*L*4)                 // int   index[V*TOPK]
#define TC_OFF  (IDX_OFF + V*TOPK*4)      // float tmp_corr[B*V*TOPK]

typedef float f32x4 __attribute__((ext_vector_type(4)));
typedef _Float16 f16x8 __attribute__((ext_vector_type(8)));   // MFMA operand type
typedef __fp16 fp16x2 __attribute__((ext_vector_type(2)));    // cvt_pkrtz result type

union F16X8U { f16x8 v; fp16x2 h[4]; };

// Split 8 f32 (two float4s) into hi/lo f16x8 via v_cvt_pkrtz.
// x = hi + r exactly (Sterbenz: hi in [x/2, 2x]); lo = rtz(r); dropped
// lo*lo MFMA term ~2^-20 relative — far below task tolerance.
__device__ __forceinline__ void split_frag(const float4 a, const float4 b,
                                           f16x8& hi, f16x8& lo) {
    F16X8U uh, ul;
    uh.h[0] = __builtin_amdgcn_cvt_pkrtz(a.x, a.y);
    uh.h[1] = __builtin_amdgcn_cvt_pkrtz(a.z, a.w);
    uh.h[2] = __builtin_amdgcn_cvt_pkrtz(b.x, b.y);
    uh.h[3] = __builtin_amdgcn_cvt_pkrtz(b.z, b.w);
    ul.h[0] = __builtin_amdgcn_cvt_pkrtz(a.x - (float)uh.h[0].x, a.y - (float)uh.h[0].y);
    ul.h[1] = __builtin_amdgcn_cvt_pkrtz(a.z - (float)uh.h[1].x, a.w - (float)uh.h[1].y);
    ul.h[2] = __builtin_amdgcn_cvt_pkrtz(b.x - (float)uh.h[2].x, b.y - (float)uh.h[2].y);
    ul.h[3] = __builtin_amdgcn_cvt_pkrtz(b.z - (float)uh.h[3].x, b.w - (float)uh.h[3].y);
    hi = uh.v; lo = ul.v;
}

// ---------------------------------------------------------------------------
// Kernel 0: zero the mv accumulator (graph-capture-safe replacement for
// hipMemsetAsync). B*V*L = 79488 floats = 19872 float4.
// ---------------------------------------------------------------------------
__global__ __launch_bounds__(256) void zero_mv_kernel(float4* __restrict__ mv4) {
    const int i = blockIdx.x * 256 + threadIdx.x;
    if (i < (B * V * L) / 4) mv4[i] = make_float4(0.f, 0.f, 0.f, 0.f);
}

// ---------------------------------------------------------------------------
// Kernel 1: per (b,v,chunk-of-128-ch): partial mean-corr via MFMA Gram matrix,
// atomically accumulated into mv. Staging: global_load_lds width-16 into
// unpadded 96x32 LDS rows, with 3-bit source pre-swizzle: LDS slot s of row t
// holds global 16B-slot s^(t&7). Each 8-lane row group still reads a
// contiguous (permuted) 128B from global; each fragment ds_read_b128 then
// spreads 8 lanes onto each of the 8 slot groups -> all 32 banks, conflict-
// free. 4 waves in 2x2 grid, each owning 48x48 of S = 3x3 16x16 tiles, K=32.
// ---------------------------------------------------------------------------
__global__ __launch_bounds__(256, 4) void corr_mean_kernel(
        const float* __restrict__ q, const float* __restrict__ k,
        float* __restrict__ mv) {
    __shared__ __attribute__((aligned(16))) float Qs[L * CCH];
    __shared__ __attribute__((aligned(16))) float Ks[L * CCH];
    __shared__ float corr[L];

    // XCD-chunked bijective swizzle: 3312 = 8*414.
    const int p = blockIdx.x;
    const int bid = (p & 7) * ((B * V * NCH) / 8) + (p >> 3);
    const int chunk = bid / (B * V);       // 0..3 -> channels [chunk*128, +128)
    const int bvi = bid % (B * V);
    const int b = bvi / V;
    const int v = bvi % V;
    const int tid = threadIdx.x;
    const int lane = tid & 63;
    const int wave = tid >> 6;
    const int lrow = lane & 15;
    const int lq = lane >> 4;
    const int rbase = (wave >> 1) * 48;
    const int cbase = (wave & 1) * 48;

    const size_t base = ((size_t)b * L * V + v) * (size_t)C;
    const int cb = chunk * (C / NCH);

    // staging lane constants: per wave-step, 8 rows x 8 slots of 16B.
    const int trow = lane >> 3;                 // row-within-group 0..7
    const int srcs = (lane & 7) ^ trow;         // pre-swizzled global slot
    // fragment read offsets (floats within row): slots (2lq)^(t&7), ^1.
    const int t7 = lrow & 7;
    const int fo0 = ((2 * lq) ^ t7) << 2;
    const int fo1 = fo0 ^ 4;

    f32x4 acc[3][3];
#pragma unroll
    for (int i = 0; i < 3; i++)
#pragma unroll
        for (int j = 0; j < 3; j++) acc[i][j] = (f32x4){0.f, 0.f, 0.f, 0.f};

    for (int jc = 0; jc < (C / NCH) / CCH; jc++) {
        const int c0 = cb + jc * CCH;
        // Stage Q and K: 12 wave-steps of 64x16B; wave w takes g = w*3+i.
#pragma unroll
        for (int i = 0; i < 3; i++) {
            const int g = wave * 3 + i;
            const int t = g * 8 + trow;
            const size_t goff = base + (size_t)t * LS + c0 + srcs * 4;
            __builtin_amdgcn_global_load_lds(
                (const __attribute__((address_space(1))) void*)(q + goff),
                (__attribute__((address_space(3))) void*)(Qs + g * 256), 16, 0, 0);
            __builtin_amdgcn_global_load_lds(
                (const __attribute__((address_space(1))) void*)(k + goff),
                (__attribute__((address_space(3))) void*)(Ks + g * 256), 16, 0, 0);
        }
        __syncthreads();

        f16x8 qhi[3], qlo[3], khi[3], klo[3];
#pragma unroll
        for (int ti = 0; ti < 3; ti++) {
            const float* pr = Qs + (rbase + ti * 16 + lrow) * CCH;
            split_frag(*(const float4*)(pr + fo0), *(const float4*)(pr + fo1),
                       qhi[ti], qlo[ti]);
        }
#pragma unroll
        for (int tj = 0; tj < 3; tj++) {
            const float* pr = Ks + (cbase + tj * 16 + lrow) * CCH;
            split_frag(*(const float4*)(pr + fo0), *(const float4*)(pr + fo1),
                       khi[tj], klo[tj]);
        }
#pragma unroll
        for (int ti = 0; ti < 3; ti++)
#pragma unroll
            for (int tj = 0; tj < 3; tj++) {
                acc[ti][tj] = __builtin_amdgcn_mfma_f32_16x16x32_f16(
                    qhi[ti], khi[tj], acc[ti][tj], 0, 0, 0);
                acc[ti][tj] = __builtin_amdgcn_mfma_f32_16x16x32_f16(
                    qhi[ti], klo[tj], acc[ti][tj], 0, 0, 0);
                acc[ti][tj] = __builtin_amdgcn_mfma_f32_16x16x32_f16(
                    qlo[ti], khi[tj], acc[ti][tj], 0, 0, 0);
            }
        __syncthreads();
    }

    if (tid < L) corr[tid] = 0.f;
    __syncthreads();

    // C/D layout (m89): col = lane&15, row = lq*4 + reg.
    // acc[ti][tj] reg r = S[rbase+16ti+lq*4+r][cbase+16tj+lrow], tau=(t1-t2)%96
#pragma unroll
    for (int d = -2; d <= 2; d++) {
        f32x4 s = (f32x4){0.f, 0.f, 0.f, 0.f};
#pragma unroll
        for (int ti = 0; ti < 3; ti++) {
            const int tj = ti - d;
            if (tj >= 0 && tj < 3) s += acc[ti][tj];
        }
#pragma unroll
        for (int r = 0; r < 4; r++) {
            int tau = rbase - cbase + d * 16 + lq * 4 + r - lrow;
            tau = ((tau % L) + L) % L;
            atomicAdd(&corr[tau], s[r]);
        }
    }
    __syncthreads();

    if (tid < L)
        atomicAdd(&mv[((size_t)b * V + v) * L + tid], corr[tid] * (1.0f / 512.0f));
}

// ---------------------------------------------------------------------------
// Kernel 2: per v — sum over b, wave-parallel top-4 (shfl butterfly,
// smaller-index tie-break), per-b softmax of gathered weights. 1 wave.
// ---------------------------------------------------------------------------
__global__ __launch_bounds__(64) void topk_softmax_kernel(
        const float* __restrict__ mv, int* __restrict__ idx,
        float* __restrict__ tc) {
    __shared__ float gm[L];
    __shared__ int sidx[TOPK];
    const int v = blockIdx.x;
    const int tid = threadIdx.x;   // 0..63

    {
        float s0 = 0.f, s1 = 0.f;
#pragma unroll
        for (int b = 0; b < B; b++) {
            s0 += mv[((size_t)b * V + v) * L + tid];
            if (tid < 32) s1 += mv[((size_t)b * V + v) * L + 64 + tid];
        }
        gm[tid] = s0;
        if (tid < 32) gm[64 + tid] = s1;
    }
    __syncthreads();

    for (int kk = 0; kk < TOPK; kk++) {
        float val = gm[tid];
        int id2 = tid;
        if (tid < 32) {
            const float v2 = gm[64 + tid];
            if (v2 > val) { val = v2; id2 = 64 + tid; }
        }
#pragma unroll
        for (int off = 32; off > 0; off >>= 1) {
            const float ov = __shfl_xor(val, off);
            const int oi = __shfl_xor(id2, off);
            if (ov > val || (ov == val && oi < id2)) { val = ov; id2 = oi; }
        }
        if (tid == 0) { sidx[kk] = id2; gm[id2] = -1e30f; }
        __syncthreads();
    }

    if (tid < B) {
        const int b = tid;
        float w[TOPK];
        float m = -1e30f;
#pragma unroll
        for (int kk = 0; kk < TOPK; kk++) {
            w[kk] = mv[((size_t)b * V + v) * L + sidx[kk]];
            m = fmaxf(m, w[kk]);
        }
        float s = 0.f;
#pragma unroll
        for (int kk = 0; kk < TOPK; kk++) { w[kk] = expf(w[kk] - m); s += w[kk]; }
        const float inv = 1.f / s;
#pragma unroll
        for (int kk = 0; kk < TOPK; kk++)
            tc[((size_t)b * V + v) * TOPK + kk] = w[kk] * inv;
    }
    if (tid < TOPK) idx[v * TOPK + tid] = sidx[tid];
}

// ---------------------------------------------------------------------------
// Kernel 3: out[b,l,v,e*8+h] = sum_kk w[b,v,kk]*values[b,(l+idx[v,kk])%L,v,h*64+e]
// One block per (b, v, e-OCTANT): e in [oct*8, oct*8+8) -> 64 output channels.
// LDS 96x68 f32 (~26 KB) -> ~6 blocks/CU. Pitch 68 rotates rows across banks;
// transposing writes <=4-way, float4 reads bank-optimal. XCD-chunked swizzle:
// octants of one (b,v) share 64B lines in one L2.
// ---------------------------------------------------------------------------
__global__ __launch_bounds__(256, 6) void agg_kernel(
        const float* __restrict__ val, const float* __restrict__ tc,
        const int* __restrict__ idx, float* __restrict__ out) {
    __shared__ __attribute__((aligned(16))) float T[L * TPAD];
    __shared__ int sidx[TOPK];
    __shared__ float sw[TOPK];

    const int p = blockIdx.x;
    const int bid = (p & 7) * ((B * V * 8) / 8) + (p >> 3);   // 6624 = 8*828
    const int oct = bid & 7;              // e in [oct*8, oct*8+8)
    const int bv = bid >> 3;
    const int b = bv / V;
    const int v = bv % V;
    const int tid = threadIdx.x;
    const int e0 = oct * 8;

    const size_t base = ((size_t)b * L * V + v) * (size_t)C;

    if (tid < TOPK) {
        sidx[tid] = idx[v * TOPK + tid];
        sw[tid] = tc[((size_t)b * V + v) * TOPK + tid];
    }

    // Stage with transpose: id in [0,1536): l = id>>4, h = (id&15)>>1, f4 = id&1.
    // Input float4 = V[l][h*64 + e0 + f4*4 + s]; store at T[l][(f4*4+s)*8 + h].
#pragma unroll
    for (int it = 0; it < 6; it++) {
        const int id = tid + it * 256;
        const int l = id >> 4;
        const int h = (id & 15) >> 1;
        const int f4 = id & 1;
        const float4 r = *(const float4*)(val + base + (size_t)l * LS + h * 64 + e0 + f4 * 4);
        float* dst = T + l * TPAD + f4 * 32 + h;
        dst[0]  = r.x;
        dst[8]  = r.y;
        dst[16] = r.z;
        dst[24] = r.w;
    }
    __syncthreads();

    const float w0 = sw[0], w1 = sw[1], w2 = sw[2], w3 = sw[3];
    const int i0 = sidx[0], i1 = sidx[1], i2 = sidx[2], i3 = sidx[3];

    // Output: id in [0,1536): l = id>>4, m = id&15 -> float4 at channel
    // oct*64 + 4m (coalesced).
#pragma unroll
    for (int it = 0; it < 6; it++) {
        const int id = tid + it * 256;
        const int l = id >> 4;
        const int m = id & 15;
        int l0 = l + i0; if (l0 >= L) l0 -= L;
        int l1 = l + i1; if (l1 >= L) l1 -= L;
        int l2 = l + i2; if (l2 >= L) l2 -= L;
        int l3 = l + i3; if (l3 >= L) l3 -= L;
        const float4 r0 = *(const float4*)(T + l0 * TPAD + m * 4);
        const float4 r1 = *(const float4*)(T + l1 * TPAD + m * 4);
        const float4 r2 = *(const float4*)(T + l2 * TPAD + m * 4);
        const float4 r3 = *(const float4*)(T + l3 * TPAD + m * 4);
        float4 o;
        o.x = w0 * r0.x + w1 * r1.x + w2 * r2.x + w3 * r3.x;
        o.y = w0 * r0.y + w1 * r1.y + w2 * r2.y + w3 * r3.y;
        o.z = w0 * r0.z + w1 * r1.z + w2 * r2.z + w3 * r3.z;
        o.w = w0 * r0.w + w1 * r1.w + w2 * r2.w + w3 * r3.w;
        *(float4*)(out + base + (size_t)l * LS + oct * 64 + m * 4) = o;
    }
}

extern "C" void kernel_launch(void* const* d_in, const int* in_sizes, int n_in,
                              void* d_out, int out_size, void* d_ws, size_t ws_size,
                              hipStream_t stream) {
    const float* q = (const float*)d_in[0];
    const float* k = (const float*)d_in[1];
    const float* val = (const float*)d_in[2];
    float* out = (float*)d_out;
    char* ws = (char*)d_ws;
    float* mv = (float*)(ws + MV_OFF);
    int* idx = (int*)(ws + IDX_OFF);
    float* tc = (float*)(ws + TC_OFF);

    zero_mv_kernel<<<(B * V * L / 4 + 255) / 256, 256, 0, stream>>>((float4*)mv);
    corr_mean_kernel<<<B * V * NCH, 256, 0, stream>>>(q, k, mv);
    topk_softmax_kernel<<<V, 64, 0, stream>>>(mv, idx, tc);
    agg_kernel<<<B * V * 8, 256, 0, stream>>>(val, tc, idx, out);
}